// Round 1
// baseline (683.970 us; speedup 1.0000x reference)
//
#include <hip/hip_runtime.h>
#include <cstdint>

// Problem constants: T_OBS=16, T_FUT=14, D=66
#define ROW   1056   // floats per train_pose row
#define ROW2  528    // float2 per train_pose row
#define VEL2  495    // float2 velocity elements ((16-1)*66/2)
#define FUT   924    // floats per output row

__global__ void nn_init(unsigned long long* best) {
    if (threadIdx.x == 0 && blockIdx.x == 0)
        *best = 0xFFFFFFFFFFFFFFFFull;
}

// block=256 (4 waves); __launch_bounds__(256,4) caps VGPR at 128 -> 16 waves/CU,
// each wave keeps 32 dwordx2 loads (16 KB) in flight per row-pair iteration.
__global__ __launch_bounds__(256, 4) void nn_dist(const float* __restrict__ obs,
                                                  const float* __restrict__ train,
                                                  int N,
                                                  unsigned long long* best) {
    const int lane = threadIdx.x & 63;
    const int wave = threadIdx.x >> 6;
    const int wpb  = blockDim.x >> 6;                     // 4
    const long long gwave   = (long long)blockIdx.x * wpb + wave;
    const long long wstride = (long long)gridDim.x * wpb; // 8192

    const float2* __restrict__ obs2 = (const float2*)obs;
    const float2* __restrict__ tr2  = (const float2*)train;

    // Query velocity diffs, float2 granularity: q[k] for j = lane + 64k.
    // k=0..6 always in-bounds (max j = 447 < 495); k=7 valid for lane < 47.
    const bool t7 = (lane < (VEL2 - 448));                // lane < 47
    float qx[8], qy[8];
    #pragma unroll
    for (int k = 0; k < 7; ++k) {
        int j = lane + 64 * k;
        float2 a = obs2[j], b = obs2[j + 33];
        qx[k] = b.x - a.x;  qy[k] = b.y - a.y;
    }
    if (t7) {
        int j = lane + 448;
        float2 a = obs2[j], b = obs2[j + 33];
        qx[7] = b.x - a.x;  qy[7] = b.y - a.y;
    } else { qx[7] = 0.f; qy[7] = 0.f; }

    unsigned long long bestKey = 0xFFFFFFFFFFFFFFFFull;

    // Two rows per iteration: two independent load batches + reduce chains.
    for (long long n = 2 * gwave; n < N; n += 2 * wstride) {
        const bool have1 = (n + 1 < N);                   // always true for even N
        const float2* __restrict__ r0 = tr2 + n * ROW2;
        const float2* __restrict__ r1 = have1 ? (r0 + ROW2) : r0;

        float s0 = 0.f, s1 = 0.f;
        #pragma unroll
        for (int k = 0; k < 7; ++k) {
            int j = lane + 64 * k;
            float2 a0 = r0[j], b0 = r0[j + 33];
            float2 a1 = r1[j], b1 = r1[j + 33];
            float dx0 = b0.x - a0.x - qx[k], dy0 = b0.y - a0.y - qy[k];
            float dx1 = b1.x - a1.x - qx[k], dy1 = b1.y - a1.y - qy[k];
            s0 += dx0 * dx0 + dy0 * dy0;
            s1 += dx1 * dx1 + dy1 * dy1;
        }
        if (t7) {
            int j = lane + 448;
            float2 a0 = r0[j], b0 = r0[j + 33];
            float2 a1 = r1[j], b1 = r1[j + 33];
            float dx0 = b0.x - a0.x - qx[7], dy0 = b0.y - a0.y - qy[7];
            float dx1 = b1.x - a1.x - qx[7], dy1 = b1.y - a1.y - qy[7];
            s0 += dx0 * dx0 + dy0 * dy0;
            s1 += dx1 * dx1 + dy1 * dy1;
        }

        // two independent 64-lane butterfly sums (chains overlap)
        #pragma unroll
        for (int off = 32; off > 0; off >>= 1) {
            s0 += __shfl_xor(s0, off, 64);
            s1 += __shfl_xor(s1, off, 64);
        }

        // packed (dist_bits<<32)|idx: min == argmin with smallest-index ties
        unsigned long long k0 =
            ((unsigned long long)__float_as_uint(s0) << 32) | (unsigned)n;
        if (k0 < bestKey) bestKey = k0;
        if (have1) {
            unsigned long long k1 =
                ((unsigned long long)__float_as_uint(s1) << 32) | (unsigned)(n + 1);
            if (k1 < bestKey) bestKey = k1;
        }
    }

    __shared__ unsigned long long wbest[4];
    if (lane == 0) wbest[wave] = bestKey;
    __syncthreads();
    if (threadIdx.x == 0) {
        unsigned long long k0 = wbest[0];
        for (int w = 1; w < wpb; ++w)
            k0 = (wbest[w] < k0) ? wbest[w] : k0;
        atomicMin(best, k0);                              // one atomic per block
    }
}

__global__ void nn_gather(const unsigned long long* best,
                          const float* __restrict__ fut,
                          float* __restrict__ out) {
    const int idx = (int)(unsigned)(*best & 0xFFFFFFFFull);
    const float4* __restrict__ src = (const float4*)(fut + (long long)idx * FUT);
    float4* __restrict__ dst = (float4*)out;
    for (int i = threadIdx.x; i < FUT / 4; i += blockDim.x)  // 231 x 16B
        dst[i] = src[i];
}

extern "C" void kernel_launch(void* const* d_in, const int* in_sizes, int n_in,
                              void* d_out, int out_size, void* d_ws, size_t ws_size,
                              hipStream_t stream) {
    const float* obs   = (const float*)d_in[0];   // (1, 16, 66)
    const float* train = (const float*)d_in[1];   // (N, 16, 66)
    const float* fut   = (const float*)d_in[2];   // (N, 14, 66)
    float* out = (float*)d_out;                   // (1, 14, 66)
    const int N = in_sizes[1] / ROW;              // 100000

    unsigned long long* best = (unsigned long long*)d_ws;

    nn_init<<<1, 64, 0, stream>>>(best);
    nn_dist<<<2048, 256, 0, stream>>>(obs, train, N, best);
    nn_gather<<<1, 256, 0, stream>>>(best, fut, out);
}

// Round 2
// 678.898 us; speedup vs baseline: 1.0075x; 1.0075x over previous
//
#include <hip/hip_runtime.h>
#include <cstdint>

// Problem constants: T_OBS=16, T_FUT=14, D=66
#define ROW   1056   // floats per train_pose row
#define ROW2  528    // float2 per train_pose row
#define VEL2  495    // float2 velocity elements ((16-1)*66/2)
#define FUT   924    // floats per output row
#define GRID  2048

// Single-read restructure: each byte of train is loaded from global exactly
// once (9 float2 loads/row). The +33-float2 velocity partner b[j+33] is
// obtained via cross-lane bpermute: with j = lane + 64k, element j+33 lives
// in lane (lane+33)&63 of group k (lane<31) or group k+1 (lane>=31).
// This removes the 1.87x dual-stream issue (and any L1/L2-miss refetch of
// the overlap window).
__global__ __launch_bounds__(256, 4) void nn_dist(const float* __restrict__ obs,
                                                  const float* __restrict__ train,
                                                  int N,
                                                  unsigned long long* __restrict__ blockBest) {
    const int lane = threadIdx.x & 63;
    const int wave = threadIdx.x >> 6;
    const long long gwave   = (long long)blockIdx.x * 4 + wave;
    const long long wstride = (long long)gridDim.x * 4;

    const float2* __restrict__ obs2 = (const float2*)obs;
    const float2* __restrict__ tr2  = (const float2*)train;

    const bool t7      = (lane < (VEL2 - 448));   // lane < 47: k=7 element valid
    const int  bsrc    = (lane + 33) & 63;        // bpermute source lane
    const bool lowHalf = (lane < 31);             // partner in group k (else k+1)

    // Query velocities (obs is 4 KB, L1-resident): simple dual-stream read.
    float qx[8], qy[8];
    #pragma unroll
    for (int k = 0; k < 7; ++k) {
        int j = lane + 64 * k;
        float2 a = obs2[j], b = obs2[j + 33];
        qx[k] = b.x - a.x;  qy[k] = b.y - a.y;
    }
    if (t7) {
        int j = lane + 448;
        float2 a = obs2[j], b = obs2[j + 33];
        qx[7] = b.x - a.x;  qy[7] = b.y - a.y;
    } else { qx[7] = 0.f; qy[7] = 0.f; }

    unsigned long long bestKey = 0xFFFFFFFFFFFFFFFFull;

    for (long long n = 2 * gwave; n < N; n += 2 * wstride) {
        const bool have1 = (n + 1 < N);
        const float2* __restrict__ r0 = tr2 + n * ROW2;
        const float2* __restrict__ r1 = have1 ? (r0 + ROW2) : r0;

        // Single-read loads: groups k=0..7 cover float2 0..511; group 8
        // covers 512..527 (clamped duplicate load for lanes >= 16).
        float2 A0[9], A1[9];
        #pragma unroll
        for (int k = 0; k < 8; ++k) {
            A0[k] = r0[lane + 64 * k];
            A1[k] = r1[lane + 64 * k];
        }
        A0[8] = r0[512 + (lane & 15)];
        A1[8] = r1[512 + (lane & 15)];

        float s0 = 0.f, s1 = 0.f;
        // Rolling shuffled partners: sx/sy hold S[k] = bpermute(A[k], bsrc).
        float sx0 = __shfl(A0[0].x, bsrc, 64), sy0 = __shfl(A0[0].y, bsrc, 64);
        float sx1 = __shfl(A1[0].x, bsrc, 64), sy1 = __shfl(A1[0].y, bsrc, 64);
        #pragma unroll
        for (int k = 0; k < 8; ++k) {
            float nx0 = __shfl(A0[k + 1].x, bsrc, 64), ny0 = __shfl(A0[k + 1].y, bsrc, 64);
            float nx1 = __shfl(A1[k + 1].x, bsrc, 64), ny1 = __shfl(A1[k + 1].y, bsrc, 64);
            float bx0 = lowHalf ? sx0 : nx0, by0 = lowHalf ? sy0 : ny0;
            float bx1 = lowHalf ? sx1 : nx1, by1 = lowHalf ? sy1 : ny1;
            float dx0 = bx0 - A0[k].x - qx[k], dy0 = by0 - A0[k].y - qy[k];
            float dx1 = bx1 - A1[k].x - qx[k], dy1 = by1 - A1[k].y - qy[k];
            bool valid = (k < 7) || t7;
            if (valid) {
                s0 += dx0 * dx0 + dy0 * dy0;
                s1 += dx1 * dx1 + dy1 * dy1;
            }
            sx0 = nx0; sy0 = ny0; sx1 = nx1; sy1 = ny1;
        }

        // two independent 64-lane butterfly sums (chains overlap)
        #pragma unroll
        for (int off = 32; off > 0; off >>= 1) {
            s0 += __shfl_xor(s0, off, 64);
            s1 += __shfl_xor(s1, off, 64);
        }

        // packed (dist_bits<<32)|idx: min == argmin with smallest-index ties
        unsigned long long k0 =
            ((unsigned long long)__float_as_uint(s0) << 32) | (unsigned)n;
        if (k0 < bestKey) bestKey = k0;
        if (have1) {
            unsigned long long k1 =
                ((unsigned long long)__float_as_uint(s1) << 32) | (unsigned)(n + 1);
            if (k1 < bestKey) bestKey = k1;
        }
    }

    __shared__ unsigned long long wbest[4];
    if (lane == 0) wbest[wave] = bestKey;
    __syncthreads();
    if (threadIdx.x == 0) {
        unsigned long long k0 = wbest[0];
        #pragma unroll
        for (int w = 1; w < 4; ++w)
            k0 = (wbest[w] < k0) ? wbest[w] : k0;
        blockBest[blockIdx.x] = k0;   // no atomics, no init kernel needed
    }
}

// Reduce 2048 per-block keys, then gather the winning future row.
__global__ __launch_bounds__(256) void nn_final(const unsigned long long* __restrict__ blockBest,
                                                int nb,
                                                const float* __restrict__ fut,
                                                float* __restrict__ out) {
    const int lane = threadIdx.x & 63;
    const int wave = threadIdx.x >> 6;

    unsigned long long k = 0xFFFFFFFFFFFFFFFFull;
    for (int i = threadIdx.x; i < nb; i += 256) {
        unsigned long long v = blockBest[i];
        if (v < k) k = v;
    }
    #pragma unroll
    for (int off = 32; off > 0; off >>= 1) {
        unsigned long long o = __shfl_xor(k, off, 64);
        if (o < k) k = o;
    }
    __shared__ unsigned long long ws[4];
    if (lane == 0) ws[wave] = k;
    __syncthreads();
    unsigned long long fk = ws[0];
    #pragma unroll
    for (int w = 1; w < 4; ++w)
        fk = (ws[w] < fk) ? ws[w] : fk;

    const int idx = (int)(unsigned)(fk & 0xFFFFFFFFull);
    const float4* __restrict__ src = (const float4*)(fut + (long long)idx * FUT);
    float4* __restrict__ dst = (float4*)out;
    for (int i = threadIdx.x; i < FUT / 4; i += blockDim.x)  // 231 x 16B
        dst[i] = src[i];
}

extern "C" void kernel_launch(void* const* d_in, const int* in_sizes, int n_in,
                              void* d_out, int out_size, void* d_ws, size_t ws_size,
                              hipStream_t stream) {
    const float* obs   = (const float*)d_in[0];   // (1, 16, 66)
    const float* train = (const float*)d_in[1];   // (N, 16, 66)
    const float* fut   = (const float*)d_in[2];   // (N, 14, 66)
    float* out = (float*)d_out;                   // (1, 14, 66)
    const int N = in_sizes[1] / ROW;              // 100000

    unsigned long long* blockBest = (unsigned long long*)d_ws;  // 2048 x 8 B

    nn_dist<<<GRID, 256, 0, stream>>>(obs, train, N, blockBest);
    nn_final<<<1, 256, 0, stream>>>(blockBest, GRID, fut, out);
}